// Round 2
// baseline (2375.429 us; speedup 1.0000x reference)
//
#include <hip/hip_runtime.h>

#define NA 8192
#define NB 8192
#define N_LAYERS 16
#define RPB 16          // rows per block (fixed)
#define NBLK 512        // fused-kernel grid (fixed: 2 blocks/CU)
#define NTH 512         // threads per fused block (16 cols/thread)

typedef _Float16 half_t;
typedef _Float16 half8_t __attribute__((ext_vector_type(8)));
typedef float float4_t __attribute__((ext_vector_type(4)));

// Raw barrier that does NOT drain vmcnt: LDS-visibility only. Keeps global
// prefetch loads for the next row-group in flight across the reduction.
__device__ __forceinline__ void barrier_lds() {
    asm volatile("s_waitcnt lgkmcnt(0)" ::: "memory");
    __builtin_amdgcn_s_barrier();
    asm volatile("" ::: "memory");
}

// ---------------------------------------------------------------------------
// Steady layers (1..15): block = 16-row chunk. First 2*ngE rows stream from
// compacted fp16 E; remaining rows re-read fp32 C and recompute exp.
// Per 2-row group: dot with register-resident v -> 8-wave reduce (vmcnt kept
// in flight) -> u; then reuse the same registers for the column partials.
// ---------------------------------------------------------------------------
__global__ __launch_bounds__(NTH, 4) void sink_fe(
    const half_t* __restrict__ E, const float* __restrict__ C,
    const float* __restrict__ v, const float* __restrict__ alpha,
    const float* __restrict__ d_eps, float* __restrict__ u,
    float* __restrict__ partial, int ngE)
{
    const int t = threadIdx.x;
    const int rc = blockIdx.x;
    const int row0 = rc * RPB;
    __shared__ float sred[2][16];

    // v weights for this thread's 16 columns (2 half8 groups), loaded once.
    const float4_t* vv = (const float4_t*)v;
    float4_t w[4];
#pragma unroll
    for (int k = 0; k < 2; ++k) {
        w[2 * k]     = vv[(size_t)(k * NTH + t) * 2];
        w[2 * k + 1] = vv[(size_t)(k * NTH + t) * 2 + 1];
    }

    float acc[2][8];
#pragma unroll
    for (int k = 0; k < 2; ++k)
#pragma unroll
        for (int j = 0; j < 8; ++j) acc[k][j] = 0.0f;

    const half8_t* Eb = (const half8_t*)E + (size_t)rc * (2 * ngE) * (NB / 8);
    const float4_t* Cb = (const float4_t*)C;
    const float inv_eps = 1.0f / d_eps[0];

    auto usum = [&](float rs0, float rs1, int par) -> float2 {
#pragma unroll
        for (int m = 1; m < 64; m <<= 1) {
            rs0 += __shfl_xor(rs0, m, 64);
            rs1 += __shfl_xor(rs1, m, 64);
        }
        const int lane = t & 63, wid = t >> 6;
        if (lane == 0) { sred[par][wid * 2] = rs0; sred[par][wid * 2 + 1] = rs1; }
        barrier_lds();
        float S0 = 0.0f, S1 = 0.0f;
#pragma unroll
        for (int q = 0; q < 8; ++q) { S0 += sred[par][q * 2]; S1 += sred[par][q * 2 + 1]; }
        return make_float2(S0, S1);
    };

    auto dotrow = [&](const half8_t (&h)[2]) -> float {
        float s = 0.0f;
#pragma unroll
        for (int k = 0; k < 2; ++k) {
            s += (float)h[k][0] * w[2 * k].x + (float)h[k][1] * w[2 * k].y +
                 (float)h[k][2] * w[2 * k].z + (float)h[k][3] * w[2 * k].w +
                 (float)h[k][4] * w[2 * k + 1].x + (float)h[k][5] * w[2 * k + 1].y +
                 (float)h[k][6] * w[2 * k + 1].z + (float)h[k][7] * w[2 * k + 1].w;
        }
        return s;
    };

    auto accrow = [&](float uu, const half8_t (&h)[2]) {
#pragma unroll
        for (int k = 0; k < 2; ++k)
#pragma unroll
            for (int j = 0; j < 8; ++j) acc[k][j] += uu * (float)h[k][j];
    };

    auto finish = [&](float rs0, float rs1, int g, const half8_t (&h0)[2],
                      const half8_t (&h1)[2]) {
        const int r0 = row0 + 2 * g;
        const float a0 = alpha[r0], a1 = alpha[r0 + 1];
        const float2 S = usum(rs0, rs1, g & 1);
        const float u0 = a0 / S.x, u1 = a1 / S.y;
        if (t == 0) { u[r0] = u0; u[r0 + 1] = u1; }
        accrow(u0, h0);
        accrow(u1, h1);
    };

    auto loadE = [&](half8_t (&d)[2][2], int g) {
#pragma unroll
        for (int rr = 0; rr < 2; ++rr)
#pragma unroll
            for (int k = 0; k < 2; ++k)
                d[rr][k] = Eb[(size_t)(2 * g + rr) * (NB / 8) + k * NTH + t];
    };

    auto stepE = [&](half8_t (&cur)[2][2], half8_t (&nxt)[2][2], int g, bool pf) {
        if (pf) loadE(nxt, g + 1);            // issued before dot & barrier
        const float rs0 = dotrow(cur[0]);
        const float rs1 = dotrow(cur[1]);
        finish(rs0, rs1, g, cur[0], cur[1]);
    };

    // ---- E-backed groups, double-buffered (static buffer indices) ----
    half8_t bufA[2][2], bufB[2][2];
    if (ngE > 0) {
        loadE(bufA, 0);
        int g = 0;
        while (g + 2 <= ngE) {
            stepE(bufA, bufB, g, g + 1 < ngE);
            stepE(bufB, bufA, g + 1, g + 2 < ngE);
            g += 2;
        }
        if (g < ngE) stepE(bufA, bufB, g, false);   // odd tail
    }

    // ---- C-backed tail groups (recompute exp; at most 8-ngE groups) ----
    for (int g = ngE; g < RPB / 2; ++g) {
        float4_t c[2][4];
#pragma unroll
        for (int rr = 0; rr < 2; ++rr)
#pragma unroll
            for (int k = 0; k < 2; ++k) {
                const size_t fi = (size_t)(row0 + 2 * g + rr) * (NB / 4) +
                                  (size_t)(k * NTH + t) * 2;
                c[rr][2 * k]     = Cb[fi];
                c[rr][2 * k + 1] = Cb[fi + 1];
            }
        half8_t h[2][2];
#pragma unroll
        for (int rr = 0; rr < 2; ++rr)
#pragma unroll
            for (int k = 0; k < 2; ++k) {
                const float4_t ca = c[rr][2 * k], cb = c[rr][2 * k + 1];
                h[rr][k][0] = (_Float16)__expf(-ca.x * inv_eps);
                h[rr][k][1] = (_Float16)__expf(-ca.y * inv_eps);
                h[rr][k][2] = (_Float16)__expf(-ca.z * inv_eps);
                h[rr][k][3] = (_Float16)__expf(-ca.w * inv_eps);
                h[rr][k][4] = (_Float16)__expf(-cb.x * inv_eps);
                h[rr][k][5] = (_Float16)__expf(-cb.y * inv_eps);
                h[rr][k][6] = (_Float16)__expf(-cb.z * inv_eps);
                h[rr][k][7] = (_Float16)__expf(-cb.w * inv_eps);
            }
        const float rs0 = dotrow(h[0]);
        const float rs1 = dotrow(h[1]);
        finish(rs0, rs1, g, h[0], h[1]);
    }

    // ---- column partials for this chunk ----
#pragma unroll
    for (int k = 0; k < 2; ++k) {
        float4_t o0 = {acc[k][0], acc[k][1], acc[k][2], acc[k][3]};
        float4_t o1 = {acc[k][4], acc[k][5], acc[k][6], acc[k][7]};
        float4_t* p = (float4_t*)(partial + (size_t)rc * NB +
                                  (size_t)(k * NTH + t) * 8);
        p[0] = o0;
        p[1] = o1;
    }
}

// ---------------------------------------------------------------------------
// Layer 0: v == 1 implicitly. Reads C, writes compacted fp16 E for the first
// 2*ngE rows of each chunk, computes u and column partials in one pass.
// ---------------------------------------------------------------------------
__global__ __launch_bounds__(NTH, 2) void sink_l0(
    const float* __restrict__ C, half_t* __restrict__ E,
    const float* __restrict__ alpha, const float* __restrict__ d_eps,
    float* __restrict__ u, float* __restrict__ partial, int ngE)
{
    const int t = threadIdx.x;
    const int rc = blockIdx.x;
    const int row0 = rc * RPB;
    __shared__ float sred[2][16];
    const float inv_eps = 1.0f / d_eps[0];
    const float4_t* Cb = (const float4_t*)C;
    half8_t* Eh = (half8_t*)E;

    float acc[2][8];
#pragma unroll
    for (int k = 0; k < 2; ++k)
#pragma unroll
        for (int j = 0; j < 8; ++j) acc[k][j] = 0.0f;

    auto usum = [&](float rs0, float rs1, int par) -> float2 {
#pragma unroll
        for (int m = 1; m < 64; m <<= 1) {
            rs0 += __shfl_xor(rs0, m, 64);
            rs1 += __shfl_xor(rs1, m, 64);
        }
        const int lane = t & 63, wid = t >> 6;
        if (lane == 0) { sred[par][wid * 2] = rs0; sred[par][wid * 2 + 1] = rs1; }
        barrier_lds();
        float S0 = 0.0f, S1 = 0.0f;
#pragma unroll
        for (int q = 0; q < 8; ++q) { S0 += sred[par][q * 2]; S1 += sred[par][q * 2 + 1]; }
        return make_float2(S0, S1);
    };

    auto loadC = [&](float4_t (&d)[2][4], int g) {
#pragma unroll
        for (int rr = 0; rr < 2; ++rr)
#pragma unroll
            for (int k = 0; k < 2; ++k) {
                const size_t fi = (size_t)(row0 + 2 * g + rr) * (NB / 4) +
                                  (size_t)(k * NTH + t) * 2;
                d[rr][2 * k]     = Cb[fi];
                d[rr][2 * k + 1] = Cb[fi + 1];
            }
    };

    auto stepC = [&](float4_t (&cur)[2][4], float4_t (&nxt)[2][4], int g, bool pf) {
        if (pf) loadC(nxt, g + 1);
        half8_t h[2][2];
        float rs[2];
#pragma unroll
        for (int rr = 0; rr < 2; ++rr) {
            float s = 0.0f;
#pragma unroll
            for (int k = 0; k < 2; ++k) {
                const float4_t ca = cur[rr][2 * k], cb = cur[rr][2 * k + 1];
                const float e0 = __expf(-ca.x * inv_eps);
                const float e1 = __expf(-ca.y * inv_eps);
                const float e2 = __expf(-ca.z * inv_eps);
                const float e3 = __expf(-ca.w * inv_eps);
                const float e4 = __expf(-cb.x * inv_eps);
                const float e5 = __expf(-cb.y * inv_eps);
                const float e6 = __expf(-cb.z * inv_eps);
                const float e7 = __expf(-cb.w * inv_eps);
                h[rr][k][0] = (_Float16)e0; h[rr][k][1] = (_Float16)e1;
                h[rr][k][2] = (_Float16)e2; h[rr][k][3] = (_Float16)e3;
                h[rr][k][4] = (_Float16)e4; h[rr][k][5] = (_Float16)e5;
                h[rr][k][6] = (_Float16)e6; h[rr][k][7] = (_Float16)e7;
                s += ((e0 + e1) + (e2 + e3)) + ((e4 + e5) + (e6 + e7));
            }
            rs[rr] = s;
        }
        if (g < ngE) {
#pragma unroll
            for (int rr = 0; rr < 2; ++rr)
#pragma unroll
                for (int k = 0; k < 2; ++k)
                    Eh[(size_t)(rc * 2 * ngE + 2 * g + rr) * (NB / 8) + k * NTH + t] = h[rr][k];
        }
        const int r0 = row0 + 2 * g;
        const float a0 = alpha[r0], a1 = alpha[r0 + 1];
        const float2 S = usum(rs[0], rs[1], g & 1);
        const float u0 = a0 / S.x, u1 = a1 / S.y;
        if (t == 0) { u[r0] = u0; u[r0 + 1] = u1; }
#pragma unroll
        for (int k = 0; k < 2; ++k)
#pragma unroll
            for (int j = 0; j < 8; ++j) {
                acc[k][j] += u0 * (float)h[0][k][j] + u1 * (float)h[1][k][j];
            }
    };

    float4_t bufA[2][4], bufB[2][4];
    loadC(bufA, 0);
#pragma unroll
    for (int g = 0; g < RPB / 2; g += 2) {
        stepC(bufA, bufB, g, true);
        stepC(bufB, bufA, g + 1, g + 2 < RPB / 2);
    }

#pragma unroll
    for (int k = 0; k < 2; ++k) {
        float4_t o0 = {acc[k][0], acc[k][1], acc[k][2], acc[k][3]};
        float4_t o1 = {acc[k][4], acc[k][5], acc[k][6], acc[k][7]};
        float4_t* p = (float4_t*)(partial + (size_t)rc * NB +
                                  (size_t)(k * NTH + t) * 8);
        p[0] = o0;
        p[1] = o1;
    }
}

// ---------------------------------------------------------------------------
// v[j] = beta[j] / sum_rc partial[rc][j].  256 blocks x (32 cols x 8 slices).
// ---------------------------------------------------------------------------
__global__ __launch_bounds__(256) void sink_v_combine(
    const float* __restrict__ partial, const float* __restrict__ beta,
    float* __restrict__ v)
{
    const int c = blockIdx.x * 32 + (threadIdx.x & 31);
    const int sl = threadIdx.x >> 5;
    float s = 0.0f;
#pragma unroll 4
    for (int i = sl; i < NBLK; i += 8) s += partial[(size_t)i * NB + c];
    __shared__ float sm[8][32];
    sm[sl][threadIdx.x & 31] = s;
    __syncthreads();
    if (threadIdx.x < 32) {
        float tot = 0.0f;
#pragma unroll
        for (int k = 0; k < 8; ++k) tot += sm[k][threadIdx.x];
        v[c] = beta[c] / tot;
    }
}

// ---------------------------------------------------------------------------
// f = eps*log(u), g = eps*log(v), concatenated into d_out.
// ---------------------------------------------------------------------------
__global__ __launch_bounds__(256) void sink_finalize(
    const float* __restrict__ u, const float* __restrict__ v,
    const float* __restrict__ d_eps, float* __restrict__ out)
{
    const int i = blockIdx.x * 256 + threadIdx.x;
    const float eps = d_eps[0];
    if (i < NA) {
        out[i] = eps * logf(u[i]);
    } else if (i < NA + NB) {
        out[i] = eps * logf(v[i - NA]);
    }
}

extern "C" void kernel_launch(void* const* d_in, const int* in_sizes, int n_in,
                              void* d_out, int out_size, void* d_ws, size_t ws_size,
                              hipStream_t stream)
{
    const float* alpha = (const float*)d_in[0];
    const float* beta  = (const float*)d_in[1];
    const float* C     = (const float*)d_in[2];
    const float* d_eps = (const float*)d_in[3];
    float* out = (float*)d_out;

    const size_t partialBytes = (size_t)NBLK * NB * sizeof(float);  // 16.78 MB
    const size_t vecBytes = (size_t)NA * sizeof(float);
    const size_t perK = (size_t)NBLK * NB * sizeof(half_t) / RPB * RPB; // bytes per K inc
    const size_t kInc = (size_t)NBLK * NB * sizeof(half_t) / 8;     // 512 rows * 16KB
    (void)perK;

    // Adaptive E coverage: K rows per 16-row chunk stored as fp16 (compacted),
    // sized from the ACTUAL workspace. Grid stays 512 blocks regardless.
    size_t avail = 0;
    if (ws_size > partialBytes + 2 * vecBytes)
        avail = ws_size - partialBytes - 2 * vecBytes;
    int K = (int)(avail / ((size_t)NBLK * NB * sizeof(half_t) / RPB));
    (void)kInc;
    if (K > RPB) K = RPB;
    K &= ~1;                       // even (2-row groups)
    const int ngE = K / 2;

    char* ws = (char*)d_ws;
    size_t off = 0;
    half_t* E = (half_t*)ws;
    off += (size_t)NBLK * K * NB * sizeof(half_t);
    float* partial = (float*)(ws + off); off += partialBytes;
    float* u = (float*)(ws + off); off += vecBytes;
    float* v = (float*)(ws + off);

    const dim3 blkF(NTH), blkS(256);
    const dim3 gridF(NBLK);
    const dim3 gridC(NB / 32);
    const dim3 gridFin((NA + NB) / 256);

    for (int layer = 0; layer < N_LAYERS; ++layer) {
        if (layer == 0)
            sink_l0<<<gridF, blkF, 0, stream>>>(C, E, alpha, d_eps, u, partial, ngE);
        else
            sink_fe<<<gridF, blkF, 0, stream>>>(E, C, v, alpha, d_eps, u, partial, ngE);
        sink_v_combine<<<gridC, blkS, 0, stream>>>(partial, beta, v);
    }
    sink_finalize<<<gridFin, blkS, 0, stream>>>(u, v, d_eps, out);
}